// Round 2
// baseline (139.678 us; speedup 1.0000x reference)
//
#include <hip/hip_runtime.h>
#include <hip/hip_cooperative_groups.h>

namespace cg = cooperative_groups;

#define BB 16384
#define DD 256
#define EE 8
#define HH 128
#define NBLK 512
#define CPAD 32          // counts stride in ints (128 B apart -> no same-line atomic serialization)
#define CS_S 136         // 128 + 8 bf16 pad

typedef __attribute__((ext_vector_type(8))) short short8;   // 8 bf16 = 4 VGPRs
typedef __attribute__((ext_vector_type(4))) float f32x4;

// fp32 -> bf16 round-to-nearest-even (values are finite; no NaN care needed)
__device__ __forceinline__ ushort f2bf(float f){
    const unsigned u = __float_as_uint(f);
    return (ushort)((u + 0x7fffu + ((u >> 16) & 1u)) >> 16);
}
__device__ __forceinline__ float bf2f(ushort s){
    return __uint_as_float(((unsigned)s) << 16);
}
__device__ __forceinline__ float fast_tanh(float v){
    v = fminf(fmaxf(v, -15.0f), 15.0f);
    const float a = __expf(2.0f * v);
    return (a - 1.0f) / (a + 1.0f);
}
// async global->LDS, 16B per lane; LDS dest is wave-uniform base + lane*16
__device__ __forceinline__ void gload_lds16(const void* g, void* l){
    __builtin_amdgcn_global_load_lds(
        (const __attribute__((address_space(1))) unsigned*)g,
        (__attribute__((address_space(3))) unsigned*)l, 16, 0, 0);
}

// ---------------------------------------------------------------------------
// Shared-memory overlays. Phase 1/2 (transpose + routing) and phase 3 (expert)
// never overlap in time within a block, so they share one union (49.5 KB ->
// 2 blocks/CU by LDS with headroom).
struct RT {
    float WgT[EE][DD];   // 8 KB
    int   le[64];        // slot s: e0 at [s], e1 at [32+s]
    float lw[64];
    int   loff[64];
    int   lcount[EE];
    int   lbase[EE];
};
struct P1 { float tile[64 * 68]; RT rt; };                       // 26.4 KB
struct P3 { ushort Xs[64 * DD]; ushort coreS[64 * CS_S];         // 49.5 KB
            int rid[64]; float wgt[64]; };
union ShU { P1 p1; P3 p3; };

// ---------------------------------------------------------------------------
// Weight transpose body: W1 [e][k=256][h=128] fp32 -> W1t [e][h][k] bf16;
// Wp likewise. b in [0,96): 64 W1 tiles + 32 Wp tiles of 64x64.
__device__ __forceinline__ void transpose_body(int b, int t,
    const float* __restrict__ W1, const float* __restrict__ Wp,
    ushort* __restrict__ W1t, ushort* __restrict__ Wpt, float* tile)
{
    const float* src; ushort* dst; int K;
    int k0, h0;
    if (b < 64){                                    // W1: 8e x 4kt x 2ht
        const int e = b >> 3, kt = (b >> 1) & 3, ht = b & 1;
        src = W1 + (size_t)e * DD * HH;  dst = W1t + (size_t)e * HH * DD;
        K = DD; k0 = kt * 64; h0 = ht * 64;
    } else {                                        // Wp: 8e x 2kt x 2ht
        b -= 64;
        const int e = b >> 2, kt = (b >> 1) & 1, ht = b & 1;
        src = Wp + (size_t)e * HH * HH;  dst = Wpt + (size_t)e * HH * HH;
        K = HH; k0 = kt * 64; h0 = ht * 64;
    }
    #pragma unroll
    for (int j = 0; j < 4; j++){
        const int idx = t + 256 * j;               // 1024 float4 = 64x64
        const int kk = idx >> 4, hh = (idx & 15) * 4;
        const float4 v = *(const float4*)(src + (size_t)(k0 + kk) * HH + h0 + hh);
        *(float4*)&tile[kk * 68 + hh] = v;
    }
    __syncthreads();
    #pragma unroll
    for (int j = 0; j < 4; j++){
        const int idx = t + 256 * j;
        const int hh = idx >> 4, kk = (idx & 15) * 4;
        ushort4 o;
        o.x = f2bf(tile[(kk + 0) * 68 + hh]);
        o.y = f2bf(tile[(kk + 1) * 68 + hh]);
        o.z = f2bf(tile[(kk + 2) * 68 + hh]);
        o.w = f2bf(tile[(kk + 3) * 68 + hh]);
        *(ushort4*)&dst[(size_t)(h0 + hh) * K + k0 + kk] = o;
    }
}

// ---------------------------------------------------------------------------
// Routing phase 1: gate logits + top-2 for rows [bid*32, bid*32+32).
// Results stay in LDS (rt->le / rt->lw). Also emits bf16 copy of x and zeroes
// this block's out[] rows. Gating math bit-identical to the verified version.
__device__ __forceinline__ void routing_p1(int bid, int t,
    const float* __restrict__ x, const float* __restrict__ Wg,
    float* __restrict__ out, ushort* __restrict__ xbf, RT* rt)
{
    const int rowBase = bid * 32;
    if (t < 32) out[rowBase + t] = 0.0f;
    {
        const float4* g = (const float4*)(Wg + t * EE);
        const float4 a = g[0], b = g[1];
        rt->WgT[0][t] = a.x; rt->WgT[1][t] = a.y; rt->WgT[2][t] = a.z; rt->WgT[3][t] = a.w;
        rt->WgT[4][t] = b.x; rt->WgT[5][t] = b.y; rt->WgT[6][t] = b.z; rt->WgT[7][t] = b.w;
    }
    if (t < EE) rt->lcount[t] = 0;
    __syncthreads();

    const int lane = t & 63;
    const int wid  = t >> 6;

    for (int it = 0; it < 8; it++){
        const int slot = wid * 8 + it;
        const int row  = rowBase + slot;
        const float4 xv = *(const float4*)(x + row * DD + lane * 4);
        {   // bf16 copy of x for the expert phase's swizzled async gather
            ushort4 o;
            o.x = f2bf(xv.x); o.y = f2bf(xv.y); o.z = f2bf(xv.z); o.w = f2bf(xv.w);
            *(ushort4*)&xbf[(size_t)row * DD + lane * 4] = o;
        }
        float p[EE];
        #pragma unroll
        for (int e = 0; e < EE; e++){
            const float4 w = *(const float4*)&rt->WgT[e][lane * 4];
            p[e] = xv.x * w.x + xv.y * w.y + xv.z * w.z + xv.w * w.w;
        }
        #pragma unroll
        for (int off = 32; off >= 1; off >>= 1){
            #pragma unroll
            for (int e = 0; e < EE; e++) p[e] += __shfl_down(p[e], off, 64);
        }
        if (lane == 0){
            int e0 = 0; float l0 = p[0];
            #pragma unroll
            for (int e = 1; e < EE; e++){ if (p[e] > l0){ l0 = p[e]; e0 = e; } }
            int e1 = -1; float l1 = -3.0e38f;
            #pragma unroll
            for (int e = 0; e < EE; e++){ if (e != e0 && p[e] > l1){ l1 = p[e]; e1 = e; } }
            const float tt  = __expf(l1 - l0);            // <= 1
            const float inv = 1.0f / (1.0f + tt);
            rt->le[slot]      = e0;  rt->lw[slot]      = inv;
            rt->le[32 + slot] = e1;  rt->lw[32 + slot] = tt * inv;
        }
    }
}

// Routing phase 2: block-aggregated compaction into global (counts padded).
__device__ __forceinline__ void routing_p2(int bid, int t,
    int* counts, int* __restrict__ rowids, float* __restrict__ wgts, RT* rt)
{
    __syncthreads();
    if (t < 64) rt->loff[t] = atomicAdd(&rt->lcount[rt->le[t]], 1);
    __syncthreads();
    if (t < EE) rt->lbase[t] = atomicAdd(&counts[t * CPAD], rt->lcount[t]);
    __syncthreads();
    if (t < 64){
        const int e   = rt->le[t];
        const int pos = rt->lbase[e] + rt->loff[t];
        rowids[e * BB + pos] = bid * 32 + (t & 31);
        wgts[e * BB + pos]   = rt->lw[t];
    }
}

// ---------------------------------------------------------------------------
// Expert chunk: 64 rows x one expert, MFMA bf16. Identical math to the
// verified kernel. Block = 4 waves; wave w: rows 32*(w>>1), cols 64*(w&1),
// 2x4 16x16 tiles. X staged from xbf via global_load_lds w=16; linear LDS
// dest + XOR-swizzled GLOBAL source chunk, same XOR on the read side.
__device__ void expert_chunk(int me, int start, int cnt, int t,
    const ushort* __restrict__ xbf,
    const ushort* __restrict__ W1t, const float* __restrict__ b1,
    const ushort* __restrict__ Wpt, const float* __restrict__ bp,
    const float* __restrict__ mix_logit,
    const float* __restrict__ Wo, const float* __restrict__ bo,
    const int* __restrict__ rowids, const float* __restrict__ wgts,
    float* __restrict__ out, P3* p3)
{
    __syncthreads();                       // protect LDS reuse across chunks/phases
    if (t < 64){
        const int idx = start + t;
        if (idx < cnt){ p3->rid[t] = rowids[me * BB + idx]; p3->wgt[t] = wgts[me * BB + idx]; }
        else          { p3->rid[t] = 0;                     p3->wgt[t] = 0.0f; }
    }
    __syncthreads();

    const int lane = t & 63;
    const int w    = t >> 6;

    // async gather: per wave 8 instructions x 1KB (2 rows each), zero VALU
    {
        const int rsub = lane >> 5;          // row within the pair
        const int c    = lane & 31;          // 16B chunk within row
        #pragma unroll
        for (int i = 0; i < 8; i++){
            const int row = w * 16 + i * 2 + rsub;
            const int sc  = c ^ (row & 7);   // pre-swizzled source chunk
            const ushort* gp = xbf + (size_t)p3->rid[row] * DD + sc * 8;
            gload_lds16(gp, &p3->Xs[(w * 16 + i * 2) * DD]);
        }
    }
    asm volatile("s_waitcnt vmcnt(0)" ::: "memory");
    __syncthreads();

    const int m16  = lane & 15;
    const int q    = lane >> 4;
    const int r0   = 32 * (w >> 1);
    const int c0   = 64 * (w & 1);
    const int swz  = m16 & 7;               // == row&7 for all rows this lane reads

    // ---- GEMM1: core_pre = X @ W1 + b1 ----
    f32x4 acc[2][4];
    #pragma unroll
    for (int ct = 0; ct < 4; ct++){
        const float bj = b1[me * HH + c0 + ct * 16 + m16];
        #pragma unroll
        for (int rt = 0; rt < 2; rt++) acc[rt][ct] = (f32x4){bj, bj, bj, bj};
    }
    const ushort* W1te = W1t + (size_t)me * HH * DD;
    #pragma unroll
    for (int ks = 0; ks < 8; ks++){
        const int kc = ks * 4 + q;           // 16B-chunk index of A fragment
        short8 af[2], bfr[4];
        #pragma unroll
        for (int rt = 0; rt < 2; rt++)
            af[rt] = *(const short8*)&p3->Xs[(r0 + rt * 16 + m16) * DD + ((kc ^ swz) * 8)];
        #pragma unroll
        for (int ct = 0; ct < 4; ct++)
            bfr[ct] = *(const short8*)&W1te[(size_t)(c0 + ct * 16 + m16) * DD + ks * 32 + q * 8];
        #pragma unroll
        for (int rt = 0; rt < 2; rt++)
            #pragma unroll
            for (int ct = 0; ct < 4; ct++)
                acc[rt][ct] = __builtin_amdgcn_mfma_f32_16x16x32_bf16(af[rt], bfr[ct], acc[rt][ct], 0, 0, 0);
    }

    // relu -> bf16 core into LDS (A-operand source for GEMM2 + epilogue reuse)
    #pragma unroll
    for (int rt = 0; rt < 2; rt++)
        #pragma unroll
        for (int ct = 0; ct < 4; ct++)
            #pragma unroll
            for (int j = 0; j < 4; j++){
                const int row = r0 + rt * 16 + q * 4 + j;
                const int col = c0 + ct * 16 + m16;
                p3->coreS[row * CS_S + col] = f2bf(fmaxf(acc[rt][ct][j], 0.0f));
            }
    __syncthreads();

    // ---- GEMM2: plast_pre = core @ Wp + bp ----
    #pragma unroll
    for (int ct = 0; ct < 4; ct++){
        const float bj = bp[me * HH + c0 + ct * 16 + m16];
        #pragma unroll
        for (int rt = 0; rt < 2; rt++) acc[rt][ct] = (f32x4){bj, bj, bj, bj};
    }
    const ushort* Wpte = Wpt + (size_t)me * HH * HH;
    #pragma unroll
    for (int ks = 0; ks < 4; ks++){
        const int k0 = ks * 32;
        short8 af[2], bfr[4];
        #pragma unroll
        for (int rt = 0; rt < 2; rt++)
            af[rt] = *(const short8*)&p3->coreS[(r0 + rt * 16 + m16) * CS_S + k0 + q * 8];
        #pragma unroll
        for (int ct = 0; ct < 4; ct++)
            bfr[ct] = *(const short8*)&Wpte[(size_t)(c0 + ct * 16 + m16) * HH + k0 + q * 8];
        #pragma unroll
        for (int rt = 0; rt < 2; rt++)
            #pragma unroll
            for (int ct = 0; ct < 4; ct++)
                acc[rt][ct] = __builtin_amdgcn_mfma_f32_16x16x32_bf16(af[rt], bfr[ct], acc[rt][ct], 0, 0, 0);
    }

    // ---- epilogue: out_row = sum_h [core*(1-m) + m*tanh(plast)] * Wo + bo ----
    const float mv  = 1.0f / (1.0f + __expf(-mix_logit[me]));
    const float om  = 1.0f - mv;
    const float bov = bo[me];
    float wo[4];
    #pragma unroll
    for (int ct = 0; ct < 4; ct++) wo[ct] = Wo[me * HH + c0 + ct * 16 + m16];

    float red[2][4];
    #pragma unroll
    for (int rt = 0; rt < 2; rt++)
        #pragma unroll
        for (int j = 0; j < 4; j++){
            float s = 0.0f;
            const int row = r0 + rt * 16 + q * 4 + j;
            #pragma unroll
            for (int ct = 0; ct < 4; ct++){
                const int col = c0 + ct * 16 + m16;
                const float pl = fast_tanh(acc[rt][ct][j]);
                const float cv = bf2f(p3->coreS[row * CS_S + col]);
                s = fmaf(om * cv + mv * pl, wo[ct], s);
            }
            red[rt][j] = s;
        }
    #pragma unroll
    for (int off = 8; off >= 1; off >>= 1)
        #pragma unroll
        for (int rt = 0; rt < 2; rt++)
            #pragma unroll
            for (int j = 0; j < 4; j++)
                red[rt][j] += __shfl_xor(red[rt][j], off, 64);   // reduce over m16

    if (m16 == 0){
        const float bb = (c0 == 0) ? bov : 0.0f;   // bias from one col-half only
        #pragma unroll
        for (int rt = 0; rt < 2; rt++)
            #pragma unroll
            for (int j = 0; j < 4; j++){
                const int row = r0 + rt * 16 + q * 4 + j;
                const float ww = p3->wgt[row];
                if (ww != 0.0f) atomicAdd(&out[p3->rid[row]], (red[rt][j] + bb) * ww);
            }
    }
}

// ---------------------------------------------------------------------------
// Fused cooperative kernel: 512 persistent blocks.
//   phase 1: counts zero (blk 0) + weight transpose (blks 0..95, extra work)
//            + routing dots/top-2 (all blocks, results persist in LDS) + xbf
//   sync    (protects counts-zero -> atomics, weights/xbf -> expert)
//   phase 2: compaction atomics, rowids/wgts writes
//   sync    (rowids/wgts/counts -> expert)
//   phase 3: expert chunks; v = sc*8 + e so active chunks (sc*64 < cnt_e)
//            are the low v's -> block b's first chunk v=b, ~1 active/block.
__global__ __launch_bounds__(256, 2) void fused_kernel(
    const float* __restrict__ x, const float* __restrict__ Wg,
    const float* __restrict__ W1, const float* __restrict__ b1,
    const float* __restrict__ Wp, const float* __restrict__ bp,
    const float* __restrict__ ml, const float* __restrict__ Wo,
    const float* __restrict__ bo,
    int* counts, int* rowids, float* wgts,
    ushort* W1t, ushort* Wpt, ushort* xbf, float* out)
{
    __shared__ ShU sh;
    const int bid = blockIdx.x;
    const int t   = threadIdx.x;

    if (bid == 0 && t < EE) counts[t * CPAD] = 0;
    if (bid < 96) transpose_body(bid, t, W1, Wp, W1t, Wpt, sh.p1.tile);
    routing_p1(bid, t, x, Wg, out, xbf, &sh.p1.rt);

    cg::this_grid().sync();

    routing_p2(bid, t, counts, rowids, wgts, &sh.p1.rt);

    cg::this_grid().sync();

    #pragma unroll 1
    for (int v = bid; v < EE * 256; v += NBLK){
        const int me    = v & 7;
        const int start = (v >> 3) * 64;
        const int cnt   = counts[me * CPAD];
        if (start < cnt)
            expert_chunk(me, start, cnt, t, xbf, W1t, b1, Wpt, bp, ml, Wo, bo,
                         rowids, wgts, out, &sh.p3);
    }
}

// ---------------------------------------------------------------------------
// Fallback 3-dispatch path (used only if cooperative launch is not viable).
__global__ __launch_bounds__(256) void transpose_kernel(
    const float* __restrict__ W1, const float* __restrict__ Wp,
    ushort* __restrict__ W1t, ushort* __restrict__ Wpt, int* __restrict__ counts)
{
    __shared__ float tile[64 * 68];
    const int t = threadIdx.x;
    if (blockIdx.x == 0 && t < EE) counts[t * CPAD] = 0;
    transpose_body(blockIdx.x, t, W1, Wp, W1t, Wpt, tile);
}

__global__ __launch_bounds__(256) void routing_kernel(
    const float* __restrict__ x, const float* __restrict__ Wg,
    int* counts, int* __restrict__ rowids, float* __restrict__ wgts,
    float* __restrict__ out, ushort* __restrict__ xbf)
{
    __shared__ RT rt;
    routing_p1(blockIdx.x, threadIdx.x, x, Wg, out, xbf, &rt);
    routing_p2(blockIdx.x, threadIdx.x, counts, rowids, wgts, &rt);
}

__global__ __launch_bounds__(256, 2) void expert_kernel(
    const ushort* __restrict__ xbf,
    const ushort* __restrict__ W1t, const float* __restrict__ b1,
    const ushort* __restrict__ Wpt, const float* __restrict__ bp,
    const float* __restrict__ ml,
    const float* __restrict__ Wo, const float* __restrict__ bo,
    const int* __restrict__ counts, const int* __restrict__ rowids,
    const float* __restrict__ wgts, float* __restrict__ out)
{
    const int me    = blockIdx.y;
    const int cnt   = counts[me * CPAD];
    const int start = blockIdx.x * 64;
    if (start >= cnt) return;
    __shared__ P3 p3;
    expert_chunk(me, start, cnt, threadIdx.x, xbf, W1t, b1, Wpt, bp, ml, Wo, bo,
                 rowids, wgts, out, &p3);
}

// ---------------------------------------------------------------------------
extern "C" void kernel_launch(void* const* d_in, const int* in_sizes, int n_in,
                              void* d_out, int out_size, void* d_ws, size_t ws_size,
                              hipStream_t stream) {
    (void)in_sizes; (void)n_in; (void)out_size; (void)ws_size;
    const float* x   = (const float*)d_in[0];
    const float* Wg  = (const float*)d_in[1];
    const float* W1  = (const float*)d_in[2];
    const float* b1  = (const float*)d_in[3];
    const float* Wp  = (const float*)d_in[4];
    const float* bp  = (const float*)d_in[5];
    const float* ml  = (const float*)d_in[6];
    const float* Wo  = (const float*)d_in[7];
    const float* bo  = (const float*)d_in[8];
    float* out = (float*)d_out;

    // ws layout (16B-aligned blocks):
    //   counts 1024B (padded) | rowids E*B*4 | wgts E*B*4 | W1t | Wpt | xbf
    char* ws = (char*)d_ws;
    int*    counts = (int*)ws;
    int*    rowids = (int*)(ws + 1024);
    float*  wgts   = (float*)(ws + 1024 + (size_t)EE * BB * 4);
    ushort* W1t    = (ushort*)(ws + 1024 + 2 * (size_t)EE * BB * 4);
    ushort* Wpt    = W1t + (size_t)EE * HH * DD;
    ushort* xbf    = Wpt + (size_t)EE * HH * HH;

    // One-time host-side viability check (host queries only -- graph-capture safe).
    static int coop_ok = -1;
    if (coop_ok < 0){
        int dev = 0; hipGetDevice(&dev);
        int sup = 0; hipDeviceGetAttribute(&sup, hipDeviceAttributeCooperativeLaunch, dev);
        int ncu = 0; hipDeviceGetAttribute(&ncu, hipDeviceAttributeMultiprocessorCount, dev);
        int nb  = 0; hipOccupancyMaxActiveBlocksPerMultiprocessor(&nb, fused_kernel, 256, 0);
        coop_ok = (sup && ncu > 0 && nb * ncu >= NBLK) ? 1 : 0;
    }

    if (coop_ok == 1){
        void* args[] = { (void*)&x, (void*)&Wg, (void*)&W1, (void*)&b1, (void*)&Wp,
                         (void*)&bp, (void*)&ml, (void*)&Wo, (void*)&bo,
                         (void*)&counts, (void*)&rowids, (void*)&wgts,
                         (void*)&W1t, (void*)&Wpt, (void*)&xbf, (void*)&out };
        hipError_t err = hipLaunchCooperativeKernel(fused_kernel, dim3(NBLK), dim3(256),
                                                    args, 0, stream);
        if (err == hipSuccess) return;
        coop_ok = 0;   // fall through to 3-dispatch path
    }

    transpose_kernel<<<96, 256, 0, stream>>>(W1, Wp, W1t, Wpt, counts);
    routing_kernel<<<BB / 32, 256, 0, stream>>>(x, Wg, counts, rowids, wgts, out, xbf);
    expert_kernel<<<dim3(BB / 64, EE), 256, 0, stream>>>(
        xbf, W1t, b1, Wpt, bp, ml, Wo, bo, counts, rowids, wgts, out);
}